// Round 6
// baseline (193.815 us; speedup 1.0000x reference)
//
#include <hip/hip_runtime.h>

#define Bq 8
#define Sq 1024
#define Dq 512

typedef __attribute__((ext_vector_type(8))) short bf16x8;
typedef __attribute__((ext_vector_type(4))) float f32x4;

__device__ __forceinline__ unsigned short f2bf(float f) {
  unsigned int u = __float_as_uint(f);
  return (unsigned short)((u + 0x7fffu + ((u >> 16) & 1u)) >> 16);
}
__device__ __forceinline__ float bf2f(unsigned short h) {
  return __uint_as_float(((unsigned int)h) << 16);
}

__device__ __forceinline__ void load_lds16(const unsigned short* g, unsigned short* l) {
  __builtin_amdgcn_global_load_lds(
      (const __attribute__((address_space(1))) unsigned int*)g,
      (__attribute__((address_space(3))) unsigned int*)l, 16, 0, 0);
}

// ---- both weights fp32 -> bf16 in one launch ----
__global__ void convert_w(const float* __restrict__ w1, unsigned short* __restrict__ w1b,
                          const float* __restrict__ w2, unsigned short* __restrict__ w2b) {
  int blk = blockIdx.x;
  const float* src = (blk < 256) ? w1 : w2;
  unsigned short* dst = (blk < 256) ? w1b : w2b;
  int i = ((blk & 255) * 256 + threadIdx.x) * 4;
  float4 v = *(const float4*)(src + i);
  ushort4 o;
  o.x = f2bf(v.x); o.y = f2bf(v.y); o.z = f2bf(v.z); o.w = f2bf(v.w);
  *(ushort4*)(dst + i) = o;
}

// ---- fused inp pass: bf16 cast + transpose + colsum; x=batch -> XCD pin ----
__global__ void prep_inp(const float* __restrict__ inp, unsigned short* __restrict__ inp_bf,
                         unsigned short* __restrict__ inpT, float* __restrict__ colsum) {
  __shared__ unsigned short tile[32][33];
  __shared__ float csum[8][33];
  int b = blockIdx.x;
  int t0 = blockIdx.y * 32, d0 = blockIdx.z * 32;
  int tx = threadIdx.x, ty = threadIdx.y;  // 32 x 8
  const float* src = inp + ((size_t)b * Sq + t0) * Dq + d0;
  unsigned short* dbf = inp_bf + ((size_t)b * Sq + t0) * Dq + d0;
  float part = 0.f;
#pragma unroll
  for (int i = 0; i < 4; ++i) {
    float v = src[(size_t)(ty + i * 8) * Dq + tx];
    unsigned short h = f2bf(v);
    tile[ty + i * 8][tx] = h;
    dbf[(size_t)(ty + i * 8) * Dq + tx] = h;
    part += v;
  }
  csum[ty][tx] = part;
  __syncthreads();
  unsigned short* dst = inpT + (size_t)b * Dq * Sq;
#pragma unroll
  for (int i = 0; i < 4; ++i)
    dst[(size_t)(d0 + ty + i * 8) * Sq + t0 + tx] = tile[tx][ty + i * 8];
  if (ty == 0) {
    float s = 0.f;
#pragma unroll
    for (int i = 0; i < 8; ++i) s += csum[i][tx];
    atomicAdd(&colsum[b * Dq + d0 + tx], s);
  }
}

// ---- fused aspect pass: bf16 cast + exact fp32 fac ----
__global__ void prep_asp(const float* __restrict__ aspect, const float* __restrict__ colsum,
                         const float* __restrict__ lenv, unsigned short* __restrict__ asp_bf,
                         float* __restrict__ fac) {
  int row = blockIdx.x * 4 + (threadIdx.x >> 6);
  int lane = threadIdx.x & 63;
  int b = row >> 10, s = row & 1023;
  const float* a = aspect + (size_t)row * Dq + lane * 8;
  const float* c = colsum + b * Dq + lane * 8;
  float4 a0 = *(const float4*)a, a1 = *(const float4*)(a + 4);
  float4 c0 = *(const float4*)c, c1 = *(const float4*)(c + 4);
  float sum = a0.x * c0.x + a0.y * c0.y + a0.z * c0.z + a0.w * c0.w +
              a1.x * c1.x + a1.y * c1.y + a1.z * c1.z + a1.w * c1.w;
  ushort4 o0; o0.x = f2bf(a0.x); o0.y = f2bf(a0.y); o0.z = f2bf(a0.z); o0.w = f2bf(a0.w);
  ushort4 o1; o1.x = f2bf(a1.x); o1.y = f2bf(a1.y); o1.z = f2bf(a1.z); o1.w = f2bf(a1.w);
  unsigned short* dst = asp_bf + (size_t)row * Dq + lane * 8;
  *(ushort4*)dst = o0;
  *(ushort4*)(dst + 4) = o1;
#pragma unroll
  for (int o = 32; o; o >>= 1) sum += __shfl_xor(sum, o, 64);
  if (lane == 0) {
    float len = lenv[b];
    float scale = sqrtf(len);
    float f = 0.f;
    if (s < (int)len) f = 1.f / (scale * (sum / scale + 1e-4f));
    fac[row] = f;
  }
}

// ---- barrier-free streaming GEMM: C[M][N] = A[M][K] * B[N][K]^T ----
// B-tile (64 rows x 512 K, 64 KB) staged ONCE into XOR-swizzled LDS
// (granule (n,kc) at slot n*64 + (kc ^ (n&7)) -> frag ds_read_b128 is 2-way
// = free). A is streamed per-lane straight into MFMA A-fragments via plain
// global_load_dwordx4 (A frag IS a contiguous 16B of a row), register
// double-buffered -> K-loop has NO barriers: compiler emits fine-grained
// vmcnt, loads overlap MFMA. Tile 128M x 64N, 4 waves each 32x64.
// K=1024 restages B once (2 barriers mid-kernel).
struct EpiArgs {
  const float* fac;
  const unsigned short* inpb;
  const unsigned short* aspb;
  const float* lenv;
  const float* bias;
  const float* resid;
  float* outF;
  unsigned short* outBf;
};

template <int EPI, int MODE, int K>
__global__ __launch_bounds__(256, 2) void gemm_stream(
    const unsigned short* __restrict__ Ag, const unsigned short* __restrict__ Bg,
    int M, int N, long strideA, long strideB, long strideOF, long strideOBf,
    EpiArgs e) {
  __shared__ unsigned short sB[64 * 512];  // 64 KB
  int b, bm, bn;
  if (MODE == 0) { b = blockIdx.x; bm = blockIdx.y; bn = blockIdx.z; }
  else           { b = 0; bn = blockIdx.x; bm = blockIdx.y; }
  const unsigned short* Ab = Ag + (size_t)b * strideA + (size_t)bm * 128 * K;
  const unsigned short* Bb = Bg + (size_t)b * strideB + (size_t)bn * 64 * K;
  int tid = threadIdx.x;
  int lane = tid & 63, wave = tid >> 6;
  int lr = lane & 15, lq = lane >> 4;
  int x7 = lr & 7;
  int m0 = wave * 32;

  // A stream pointers: lane owns rows m0+lr and m0+16+lr, 16B chunk lq
  const unsigned short* A0 = Ab + (size_t)(m0 + lr) * K + lq * 8;
  const unsigned short* A1 = A0 + (size_t)16 * K;

  // B staging: instr per row n; lane l -> col granule l^(n&7) (coalesced 1KB)
  auto stageB = [&](int ph) {
#pragma unroll
    for (int j = 0; j < 16; ++j) {
      int n = wave * 16 + j;
      const unsigned short* src = Bb + (size_t)n * K + ph * 512 + (lane ^ (n & 7)) * 8;
      load_lds16(src, &sB[n * 512 + lane * 8]);
    }
  };

  bf16x8 abuf[2][2][4];
  auto loadA = [&](int buf, int kk) {
#pragma unroll
    for (int u = 0; u < 4; ++u) {
      abuf[buf][0][u] = *(const bf16x8*)(A0 + kk + u * 32);
      abuf[buf][1][u] = *(const bf16x8*)(A1 + kk + u * 32);
    }
  };

  f32x4 acc[2][4] = {};

  stageB(0);
  loadA(0, 0);
  __syncthreads();

  const int NI = K >> 7;  // 128-K unroll iters
#pragma unroll
  for (int ki = 0; ki < NI; ++ki) {
    if (ki > 0 && (ki & 3) == 0) {        // phase boundary (K=1024 only)
      __syncthreads();                     // all waves done with old sB
      stageB(ki >> 2);
      __syncthreads();
    }
    if (ki + 1 < NI) loadA((ki + 1) & 1, (ki + 1) * 128);
    bf16x8(&a)[2][4] = abuf[ki & 1];
    int kb = (ki & 3) * 16;                // phase-local granule base
#pragma unroll
    for (int u = 0; u < 4; ++u) {
      int kg = kb + u * 4;
      bf16x8 bv[4];
#pragma unroll
      for (int ni = 0; ni < 4; ++ni)
        bv[ni] = *(const bf16x8*)&sB[(((ni * 16 + lr) << 6) + ((kg + lq) ^ x7)) * 8];
#pragma unroll
      for (int ni = 0; ni < 4; ++ni) {
        acc[0][ni] = __builtin_amdgcn_mfma_f32_16x16x32_bf16(a[0][u], bv[ni], acc[0][ni], 0, 0, 0);
        acc[1][ni] = __builtin_amdgcn_mfma_f32_16x16x32_bf16(a[1][u], bv[ni], acc[1][ni], 0, 0, 0);
      }
    }
  }

#pragma unroll
  for (int mi = 0; mi < 2; ++mi) {
#pragma unroll
    for (int ni = 0; ni < 4; ++ni) {
#pragma unroll
      for (int i = 0; i < 4; ++i) {
        int r = bm * 128 + m0 + mi * 16 + lq * 4 + i;
        int cc = bn * 64 + ni * 16 + lr;
        float v = acc[mi][ni][i];
        if (EPI == 1) {
          float f = e.fac[(size_t)b * M + r];
          e.outBf[(size_t)b * strideOBf + (size_t)r * N + cc] = f2bf(v * f);
        } else if (EPI == 2) {
          int len = (int)e.lenv[b];
          size_t idx = (size_t)b * ((size_t)Sq * Dq) + (size_t)r * Dq + cc;
          float add = (r < len) ? (bf2f(e.inpb[idx]) + bf2f(e.aspb[idx])) : 0.f;
          float o = v + add;
          e.outF[(size_t)b * strideOF + (size_t)r * N + cc] = o;
          e.outBf[(size_t)b * strideOBf + (size_t)r * N + cc] = f2bf(o);
        } else if (EPI == 3) {
          float o = fmaxf(v + e.bias[cc], 0.f);
          e.outBf[(size_t)r * N + cc] = f2bf(o);
        } else {
          float o = fmaxf(v + e.bias[cc], 0.f);
          size_t idx = (size_t)r * N + cc;
          e.outF[idx] = 2.f * e.resid[idx] + o;
        }
      }
    }
  }
}

// ---- out[row] = final[row] / ||final[row]|| ----
__global__ void norm_kernel(const float* __restrict__ fin, float* __restrict__ out) {
  int row = blockIdx.x * 4 + (threadIdx.x >> 6);
  int lane = threadIdx.x & 63;
  const float* p = fin + (size_t)row * Dq;
  float4 v0 = *(const float4*)(p + lane * 8);
  float4 v1 = *(const float4*)(p + lane * 8 + 4);
  float ss = v0.x * v0.x + v0.y * v0.y + v0.z * v0.z + v0.w * v0.w +
             v1.x * v1.x + v1.y * v1.y + v1.z * v1.z + v1.w * v1.w;
#pragma unroll
  for (int o = 32; o; o >>= 1) ss += __shfl_xor(ss, o, 64);
  float rn = 1.f / sqrtf(ss);
  float* q = out + (size_t)row * Dq;
  v0.x *= rn; v0.y *= rn; v0.z *= rn; v0.w *= rn;
  v1.x *= rn; v1.y *= rn; v1.z *= rn; v1.w *= rn;
  *(float4*)(q + lane * 8) = v0;
  *(float4*)(q + lane * 8 + 4) = v1;
}

extern "C" void kernel_launch(void* const* d_in, const int* in_sizes, int n_in,
                              void* d_out, int out_size, void* d_ws, size_t ws_size,
                              hipStream_t stream) {
  const float* inp = (const float*)d_in[0];
  const float* inp_len = (const float*)d_in[1];
  const float* aspect = (const float*)d_in[2];
  const float* w1 = (const float*)d_in[3];
  const float* b1 = (const float*)d_in[4];
  const float* w2 = (const float*)d_in[5];
  const float* b2 = (const float*)d_in[6];
  float* out = (float*)d_out;

  char* W = (char*)d_ws;
  const size_t MB = 1ull << 20;
  unsigned short* inp_bf = (unsigned short*)(W + 0);        // 8 MB  [B][S][D]
  unsigned short* asp_bf = (unsigned short*)(W + 8 * MB);   // 8 MB  [B][S][D]
  unsigned short* inpT   = (unsigned short*)(W + 16 * MB);  // 8 MB  [B][D][S]
  unsigned short* att    = (unsigned short*)(W + 24 * MB);  // 16 MB [B][S][S] (bf16)
  float*          finalF = (float*)(W + 24 * MB);           // 16 MB (reuses att after GEMM2)
  float*          ffnF   = (float*)(W + 40 * MB);           // 16 MB [B*S][D]
  unsigned short* ffnBf  = (unsigned short*)(W + 56 * MB);  // 8 MB
  unsigned short* o1b    = (unsigned short*)(W + 64 * MB);  // 8 MB
  unsigned short* w1bf   = (unsigned short*)(W + 72 * MB);  // 512 KB
  unsigned short* w2bf   = (unsigned short*)(W + 72 * MB + 512 * 1024);
  float*          colsum = (float*)(W + 73 * MB);           // 16 KB
  float*          fac    = (float*)(W + 73 * MB + 64 * 1024);  // 32 KB

  // prep
  hipMemsetAsync(colsum, 0, Bq * Dq * sizeof(float), stream);
  prep_inp<<<dim3(8, 32, 16), dim3(32, 8), 0, stream>>>(inp, inp_bf, inpT, colsum);
  convert_w<<<512, 256, 0, stream>>>(w1, w1bf, w2, w2bf);
  prep_asp<<<2048, 256, 0, stream>>>(aspect, colsum, inp_len, asp_bf, fac);

  // GEMM1: att_n = (aspect . inp) * fac   M=1024 N=1024 K=512  (x=batch -> XCD pin)
  {
    EpiArgs e{};
    e.fac = fac; e.outBf = att;
    gemm_stream<1, 0, 512><<<dim3(8, 8, 16), 256, 0, stream>>>(
        asp_bf, inp_bf, 1024, 1024,
        (long)Sq * Dq, (long)Sq * Dq, 0, (long)Sq * Sq, e);
  }
  // GEMM2: ffn_inp = att_n @ inp + (inp+aspect)*mask   M=1024 N=512 K=1024
  {
    EpiArgs e{};
    e.inpb = inp_bf; e.aspb = asp_bf; e.lenv = inp_len; e.outF = ffnF; e.outBf = ffnBf;
    gemm_stream<2, 0, 1024><<<dim3(8, 8, 8), 256, 0, stream>>>(
        att, inpT, 1024, 512,
        (long)Sq * Sq, (long)Dq * Sq, (long)Sq * Dq, (long)Sq * Dq, e);
  }
  // GEMM3: o1 = relu(ffn @ w1^T + b1)   M=8192 N=512 K=512  (x=bn -> XCD pin on w-tile)
  {
    EpiArgs e{};
    e.bias = b1; e.outBf = o1b;
    gemm_stream<3, 1, 512><<<dim3(8, 64), 256, 0, stream>>>(
        ffnBf, w1bf, 8192, 512, 0, 0, 0, 0, e);
  }
  // GEMM4: final = 2*ffn + relu(o1 @ w2^T + b2)   M=8192 N=512 K=512
  {
    EpiArgs e{};
    e.bias = b2; e.resid = ffnF; e.outF = finalF;
    gemm_stream<4, 1, 512><<<dim3(8, 64), 256, 0, stream>>>(
        o1b, w2bf, 8192, 512, 0, 0, 0, 0, e);
  }
  // normalize rows
  norm_kernel<<<2048, 256, 0, stream>>>(finalF, out);
}

// Round 7
// 170.211 us; speedup vs baseline: 1.1387x; 1.1387x over previous
//
#include <hip/hip_runtime.h>

#define Bq 8
#define Sq 1024
#define Dq 512

typedef __attribute__((ext_vector_type(8))) short bf16x8;
typedef __attribute__((ext_vector_type(4))) float f32x4;

__device__ __forceinline__ unsigned short f2bf(float f) {
  unsigned int u = __float_as_uint(f);
  return (unsigned short)((u + 0x7fffu + ((u >> 16) & 1u)) >> 16);
}
__device__ __forceinline__ float bf2f(unsigned short h) {
  return __uint_as_float(((unsigned int)h) << 16);
}

__device__ __forceinline__ void load_lds16(const unsigned short* g, unsigned short* l) {
  __builtin_amdgcn_global_load_lds(
      (const __attribute__((address_space(1))) unsigned int*)g,
      (__attribute__((address_space(3))) unsigned int*)l, 16, 0, 0);
}

// ---- both weights fp32 -> bf16 in one launch ----
__global__ void convert_w(const float* __restrict__ w1, unsigned short* __restrict__ w1b,
                          const float* __restrict__ w2, unsigned short* __restrict__ w2b) {
  int blk = blockIdx.x;
  const float* src = (blk < 256) ? w1 : w2;
  unsigned short* dst = (blk < 256) ? w1b : w2b;
  int i = ((blk & 255) * 256 + threadIdx.x) * 4;
  float4 v = *(const float4*)(src + i);
  ushort4 o;
  o.x = f2bf(v.x); o.y = f2bf(v.y); o.z = f2bf(v.z); o.w = f2bf(v.w);
  *(ushort4*)(dst + i) = o;
}

// ---- fused inp pass: bf16 cast + transpose + colsum; x=batch -> XCD pin ----
__global__ void prep_inp(const float* __restrict__ inp, unsigned short* __restrict__ inp_bf,
                         unsigned short* __restrict__ inpT, float* __restrict__ colsum) {
  __shared__ unsigned short tile[32][33];
  __shared__ float csum[8][33];
  int b = blockIdx.x;
  int t0 = blockIdx.y * 32, d0 = blockIdx.z * 32;
  int tx = threadIdx.x, ty = threadIdx.y;  // 32 x 8
  const float* src = inp + ((size_t)b * Sq + t0) * Dq + d0;
  unsigned short* dbf = inp_bf + ((size_t)b * Sq + t0) * Dq + d0;
  float part = 0.f;
#pragma unroll
  for (int i = 0; i < 4; ++i) {
    float v = src[(size_t)(ty + i * 8) * Dq + tx];
    unsigned short h = f2bf(v);
    tile[ty + i * 8][tx] = h;
    dbf[(size_t)(ty + i * 8) * Dq + tx] = h;
    part += v;
  }
  csum[ty][tx] = part;
  __syncthreads();
  unsigned short* dst = inpT + (size_t)b * Dq * Sq;
#pragma unroll
  for (int i = 0; i < 4; ++i)
    dst[(size_t)(d0 + ty + i * 8) * Sq + t0 + tx] = tile[tx][ty + i * 8];
  if (ty == 0) {
    float s = 0.f;
#pragma unroll
    for (int i = 0; i < 8; ++i) s += csum[i][tx];
    atomicAdd(&colsum[b * Dq + d0 + tx], s);
  }
}

// ---- fused aspect pass: bf16 cast + exact fp32 fac ----
__global__ void prep_asp(const float* __restrict__ aspect, const float* __restrict__ colsum,
                         const float* __restrict__ lenv, unsigned short* __restrict__ asp_bf,
                         float* __restrict__ fac) {
  int row = blockIdx.x * 4 + (threadIdx.x >> 6);
  int lane = threadIdx.x & 63;
  int b = row >> 10, s = row & 1023;
  const float* a = aspect + (size_t)row * Dq + lane * 8;
  const float* c = colsum + b * Dq + lane * 8;
  float4 a0 = *(const float4*)a, a1 = *(const float4*)(a + 4);
  float4 c0 = *(const float4*)c, c1 = *(const float4*)(c + 4);
  float sum = a0.x * c0.x + a0.y * c0.y + a0.z * c0.z + a0.w * c0.w +
              a1.x * c1.x + a1.y * c1.y + a1.z * c1.z + a1.w * c1.w;
  ushort4 o0; o0.x = f2bf(a0.x); o0.y = f2bf(a0.y); o0.z = f2bf(a0.z); o0.w = f2bf(a0.w);
  ushort4 o1; o1.x = f2bf(a1.x); o1.y = f2bf(a1.y); o1.z = f2bf(a1.z); o1.w = f2bf(a1.w);
  unsigned short* dst = asp_bf + (size_t)row * Dq + lane * 8;
  *(ushort4*)dst = o0;
  *(ushort4*)(dst + 4) = o1;
#pragma unroll
  for (int o = 32; o; o >>= 1) sum += __shfl_xor(sum, o, 64);
  if (lane == 0) {
    float len = lenv[b];
    float scale = sqrtf(len);
    float f = 0.f;
    if (s < (int)len) f = 1.f / (scale * (sum / scale + 1e-4f));
    fac[row] = f;
  }
}

// ---- 64x64 tile, BK=64, dbuf, HIGH-OCCUPANCY bf16 MFMA GEMM: C = A*B^T ----
// 32 KB LDS total + tiny VGPR count -> 5 blocks/CU resident; grids are
// 1024-2048 blocks (4-8/CU) so barrier drains in one block overlap with
// compute/issue in 4 others (m114 co-scheduling). Coalesced swizzled
// global_load_lds staging (8 full 128B lines/instr); frag ds_read_b128 at
// the uniform 8-lane/bank-group floor. 4 waves, each a 32x32 quadrant.
struct EpiArgs {
  const float* fac;
  const unsigned short* inpb;
  const unsigned short* aspb;
  const float* lenv;
  const float* bias;
  const float* resid;
  float* outF;
  unsigned short* outBf;
};

template <int EPI, int MODE, int K>
__global__ __launch_bounds__(256, 5) void gemm_bf16(
    const unsigned short* __restrict__ Ag, const unsigned short* __restrict__ Bg,
    int M, int N, long strideA, long strideB, long strideOF, long strideOBf,
    EpiArgs e) {
  __shared__ unsigned short sA[2][64 * 64];  // 2 x 8 KB
  __shared__ unsigned short sB[2][64 * 64];  // 2 x 8 KB
  int b, bm, bn;
  if (MODE == 0) { b = blockIdx.x; bm = blockIdx.y; bn = blockIdx.z; }
  else           { b = 0; bm = blockIdx.x; bn = blockIdx.y; }
  const unsigned short* Ab = Ag + (size_t)b * strideA + (size_t)bm * 64 * K;
  const unsigned short* Bb = Bg + (size_t)b * strideB + (size_t)bn * 64 * K;
  int tid = threadIdx.x;
  int lane = tid & 63, wave = tid >> 6;
  int wm = (wave >> 1) * 32, wn = (wave & 1) * 32;
  int lr = lane & 15, lq = lane >> 4;
  int x7 = lr & 7;
  int l3 = lane >> 3, l7 = lane & 7;

  // staging: wave stages A rows wave*16..+15 and B rows same, as 2 instrs of
  // 8 rows x 128B; lane -> row +l3, mem chunk l7^l3 (LDS slot l7 of that row
  // then holds chunk l7^(row&7), since row&7 == l3 for 8-aligned bases).
  int r0 = wave * 16;
  const unsigned short* gA = Ab + (size_t)(r0 + l3) * K + (l7 ^ l3) * 8;
  const unsigned short* gB = Bb + (size_t)(r0 + l3) * K + (l7 ^ l3) * 8;
  int dbase0 = (r0 * 8 + lane) * 8;
  int dbase1 = ((r0 + 8) * 8 + lane) * 8;

  f32x4 acc[2][2] = {};

  auto issue = [&](int buf, int k0) {
    load_lds16(gA + k0, &sA[buf][dbase0]);
    load_lds16(gA + (size_t)8 * K + k0, &sA[buf][dbase1]);
    load_lds16(gB + k0, &sB[buf][dbase0]);
    load_lds16(gB + (size_t)8 * K + k0, &sB[buf][dbase1]);
  };

  const int nk = K >> 6;
  issue(0, 0);
#pragma unroll
  for (int it = 0; it < nk; ++it) {
    int cur = it & 1;
    __syncthreads();
    if (it + 1 < nk) issue(cur ^ 1, (it + 1) << 6);
#pragma unroll
    for (int c = 0; c < 2; ++c) {
      int g = c * 4 + lq;
      bf16x8 a0 = *(const bf16x8*)&sA[cur][((wm + lr) * 8 + (g ^ x7)) * 8];
      bf16x8 a1 = *(const bf16x8*)&sA[cur][((wm + 16 + lr) * 8 + (g ^ x7)) * 8];
      bf16x8 b0 = *(const bf16x8*)&sB[cur][((wn + lr) * 8 + (g ^ x7)) * 8];
      bf16x8 b1 = *(const bf16x8*)&sB[cur][((wn + 16 + lr) * 8 + (g ^ x7)) * 8];
      acc[0][0] = __builtin_amdgcn_mfma_f32_16x16x32_bf16(a0, b0, acc[0][0], 0, 0, 0);
      acc[0][1] = __builtin_amdgcn_mfma_f32_16x16x32_bf16(a0, b1, acc[0][1], 0, 0, 0);
      acc[1][0] = __builtin_amdgcn_mfma_f32_16x16x32_bf16(a1, b0, acc[1][0], 0, 0, 0);
      acc[1][1] = __builtin_amdgcn_mfma_f32_16x16x32_bf16(a1, b1, acc[1][1], 0, 0, 0);
    }
  }

#pragma unroll
  for (int mi = 0; mi < 2; ++mi) {
#pragma unroll
    for (int ni = 0; ni < 2; ++ni) {
#pragma unroll
      for (int i = 0; i < 4; ++i) {
        int r = bm * 64 + wm + mi * 16 + lq * 4 + i;
        int cc = bn * 64 + wn + ni * 16 + lr;
        float v = acc[mi][ni][i];
        if (EPI == 1) {
          float f = e.fac[(size_t)b * M + r];
          e.outBf[(size_t)b * strideOBf + (size_t)r * N + cc] = f2bf(v * f);
        } else if (EPI == 2) {
          int len = (int)e.lenv[b];
          size_t idx = (size_t)b * ((size_t)Sq * Dq) + (size_t)r * Dq + cc;
          float add = (r < len) ? (bf2f(e.inpb[idx]) + bf2f(e.aspb[idx])) : 0.f;
          float o = v + add;
          e.outF[(size_t)b * strideOF + (size_t)r * N + cc] = o;
          e.outBf[(size_t)b * strideOBf + (size_t)r * N + cc] = f2bf(o);
        } else if (EPI == 3) {
          float o = fmaxf(v + e.bias[cc], 0.f);
          e.outBf[(size_t)r * N + cc] = f2bf(o);
        } else {
          float o = fmaxf(v + e.bias[cc], 0.f);
          size_t idx = (size_t)r * N + cc;
          e.outF[idx] = 2.f * e.resid[idx] + o;
        }
      }
    }
  }
}

// ---- out[row] = final[row] / ||final[row]|| ----
__global__ void norm_kernel(const float* __restrict__ fin, float* __restrict__ out) {
  int row = blockIdx.x * 4 + (threadIdx.x >> 6);
  int lane = threadIdx.x & 63;
  const float* p = fin + (size_t)row * Dq;
  float4 v0 = *(const float4*)(p + lane * 8);
  float4 v1 = *(const float4*)(p + lane * 8 + 4);
  float ss = v0.x * v0.x + v0.y * v0.y + v0.z * v0.z + v0.w * v0.w +
             v1.x * v1.x + v1.y * v1.y + v1.z * v1.z + v1.w * v1.w;
#pragma unroll
  for (int o = 32; o; o >>= 1) ss += __shfl_xor(ss, o, 64);
  float rn = 1.f / sqrtf(ss);
  float* q = out + (size_t)row * Dq;
  v0.x *= rn; v0.y *= rn; v0.z *= rn; v0.w *= rn;
  v1.x *= rn; v1.y *= rn; v1.z *= rn; v1.w *= rn;
  *(float4*)(q + lane * 8) = v0;
  *(float4*)(q + lane * 8 + 4) = v1;
}

extern "C" void kernel_launch(void* const* d_in, const int* in_sizes, int n_in,
                              void* d_out, int out_size, void* d_ws, size_t ws_size,
                              hipStream_t stream) {
  const float* inp = (const float*)d_in[0];
  const float* inp_len = (const float*)d_in[1];
  const float* aspect = (const float*)d_in[2];
  const float* w1 = (const float*)d_in[3];
  const float* b1 = (const float*)d_in[4];
  const float* w2 = (const float*)d_in[5];
  const float* b2 = (const float*)d_in[6];
  float* out = (float*)d_out;

  char* W = (char*)d_ws;
  const size_t MB = 1ull << 20;
  unsigned short* inp_bf = (unsigned short*)(W + 0);        // 8 MB  [B][S][D]
  unsigned short* asp_bf = (unsigned short*)(W + 8 * MB);   // 8 MB  [B][S][D]
  unsigned short* inpT   = (unsigned short*)(W + 16 * MB);  // 8 MB  [B][D][S]
  unsigned short* att    = (unsigned short*)(W + 24 * MB);  // 16 MB [B][S][S] (bf16)
  float*          finalF = (float*)(W + 24 * MB);           // 16 MB (reuses att after GEMM2)
  float*          ffnF   = (float*)(W + 40 * MB);           // 16 MB [B*S][D]
  unsigned short* ffnBf  = (unsigned short*)(W + 56 * MB);  // 8 MB
  unsigned short* o1b    = (unsigned short*)(W + 64 * MB);  // 8 MB
  unsigned short* w1bf   = (unsigned short*)(W + 72 * MB);  // 512 KB
  unsigned short* w2bf   = (unsigned short*)(W + 72 * MB + 512 * 1024);
  float*          colsum = (float*)(W + 73 * MB);           // 16 KB
  float*          fac    = (float*)(W + 73 * MB + 64 * 1024);  // 32 KB

  // prep
  hipMemsetAsync(colsum, 0, Bq * Dq * sizeof(float), stream);
  prep_inp<<<dim3(8, 32, 16), dim3(32, 8), 0, stream>>>(inp, inp_bf, inpT, colsum);
  convert_w<<<512, 256, 0, stream>>>(w1, w1bf, w2, w2bf);
  prep_asp<<<2048, 256, 0, stream>>>(aspect, colsum, inp_len, asp_bf, fac);

  // GEMM1: att_n = (aspect . inp) * fac   M=1024 N=1024 K=512  (2048 blocks)
  {
    EpiArgs e{};
    e.fac = fac; e.outBf = att;
    gemm_bf16<1, 0, 512><<<dim3(8, 16, 16), 256, 0, stream>>>(
        asp_bf, inp_bf, 1024, 1024,
        (long)Sq * Dq, (long)Sq * Dq, 0, (long)Sq * Sq, e);
  }
  // GEMM2: ffn_inp = att_n @ inp + (inp+aspect)*mask   M=1024 N=512 K=1024  (1024 blocks)
  {
    EpiArgs e{};
    e.inpb = inp_bf; e.aspb = asp_bf; e.lenv = inp_len; e.outF = ffnF; e.outBf = ffnBf;
    gemm_bf16<2, 0, 1024><<<dim3(8, 16, 8), 256, 0, stream>>>(
        att, inpT, 1024, 512,
        (long)Sq * Sq, (long)Dq * Sq, (long)Sq * Dq, (long)Sq * Dq, e);
  }
  // GEMM3: o1 = relu(ffn @ w1^T + b1)   M=8192 N=512 K=512  (1024 blocks)
  {
    EpiArgs e{};
    e.bias = b1; e.outBf = o1b;
    gemm_bf16<3, 1, 512><<<dim3(128, 8), 256, 0, stream>>>(
        ffnBf, w1bf, 8192, 512, 0, 0, 0, 0, e);
  }
  // GEMM4: final = 2*ffn + relu(o1 @ w2^T + b2)   M=8192 N=512 K=512  (1024 blocks)
  {
    EpiArgs e{};
    e.bias = b2; e.resid = ffnF; e.outF = finalF;
    gemm_bf16<4, 1, 512><<<dim3(128, 8), 256, 0, stream>>>(
        o1b, w2bf, 8192, 512, 0, 0, 0, 0, e);
  }
  // normalize rows
  norm_kernel<<<2048, 256, 0, stream>>>(finalF, out);
}

// Round 8
// 157.975 us; speedup vs baseline: 1.2269x; 1.0775x over previous
//
#include <hip/hip_runtime.h>

#define Bq 8
#define Sq 1024
#define Dq 512

typedef __attribute__((ext_vector_type(8))) short bf16x8;
typedef __attribute__((ext_vector_type(4))) float f32x4;

__device__ __forceinline__ unsigned short f2bf(float f) {
  unsigned int u = __float_as_uint(f);
  return (unsigned short)((u + 0x7fffu + ((u >> 16) & 1u)) >> 16);
}
__device__ __forceinline__ float bf2f(unsigned short h) {
  return __uint_as_float(((unsigned int)h) << 16);
}

__device__ __forceinline__ void load_lds16(const unsigned short* g, unsigned short* l) {
  __builtin_amdgcn_global_load_lds(
      (const __attribute__((address_space(1))) unsigned int*)g,
      (__attribute__((address_space(3))) unsigned int*)l, 16, 0, 0);
}

// ---- both weights fp32 -> bf16 in one launch ----
__global__ void convert_w(const float* __restrict__ w1, unsigned short* __restrict__ w1b,
                          const float* __restrict__ w2, unsigned short* __restrict__ w2b) {
  int blk = blockIdx.x;
  const float* src = (blk < 256) ? w1 : w2;
  unsigned short* dst = (blk < 256) ? w1b : w2b;
  int i = ((blk & 255) * 256 + threadIdx.x) * 4;
  float4 v = *(const float4*)(src + i);
  ushort4 o;
  o.x = f2bf(v.x); o.y = f2bf(v.y); o.z = f2bf(v.z); o.w = f2bf(v.w);
  *(ushort4*)(dst + i) = o;
}

// ---- fused inp pass: bf16 cast + transpose + colsum; x=batch -> XCD pin ----
__global__ void prep_inp(const float* __restrict__ inp, unsigned short* __restrict__ inp_bf,
                         unsigned short* __restrict__ inpT, float* __restrict__ colsum) {
  __shared__ unsigned short tile[32][33];
  __shared__ float csum[8][33];
  int b = blockIdx.x;
  int t0 = blockIdx.y * 32, d0 = blockIdx.z * 32;
  int tx = threadIdx.x, ty = threadIdx.y;  // 32 x 8
  const float* src = inp + ((size_t)b * Sq + t0) * Dq + d0;
  unsigned short* dbf = inp_bf + ((size_t)b * Sq + t0) * Dq + d0;
  float part = 0.f;
#pragma unroll
  for (int i = 0; i < 4; ++i) {
    float v = src[(size_t)(ty + i * 8) * Dq + tx];
    unsigned short h = f2bf(v);
    tile[ty + i * 8][tx] = h;
    dbf[(size_t)(ty + i * 8) * Dq + tx] = h;
    part += v;
  }
  csum[ty][tx] = part;
  __syncthreads();
  unsigned short* dst = inpT + (size_t)b * Dq * Sq;
#pragma unroll
  for (int i = 0; i < 4; ++i)
    dst[(size_t)(d0 + ty + i * 8) * Sq + t0 + tx] = tile[tx][ty + i * 8];
  if (ty == 0) {
    float s = 0.f;
#pragma unroll
    for (int i = 0; i < 8; ++i) s += csum[i][tx];
    atomicAdd(&colsum[b * Dq + d0 + tx], s);
  }
}

// ---- fused aspect pass: bf16 cast + exact fp32 fac ----
__global__ void prep_asp(const float* __restrict__ aspect, const float* __restrict__ colsum,
                         const float* __restrict__ lenv, unsigned short* __restrict__ asp_bf,
                         float* __restrict__ fac) {
  int row = blockIdx.x * 4 + (threadIdx.x >> 6);
  int lane = threadIdx.x & 63;
  int b = row >> 10, s = row & 1023;
  const float* a = aspect + (size_t)row * Dq + lane * 8;
  const float* c = colsum + b * Dq + lane * 8;
  float4 a0 = *(const float4*)a, a1 = *(const float4*)(a + 4);
  float4 c0 = *(const float4*)c, c1 = *(const float4*)(c + 4);
  float sum = a0.x * c0.x + a0.y * c0.y + a0.z * c0.z + a0.w * c0.w +
              a1.x * c1.x + a1.y * c1.y + a1.z * c1.z + a1.w * c1.w;
  ushort4 o0; o0.x = f2bf(a0.x); o0.y = f2bf(a0.y); o0.z = f2bf(a0.z); o0.w = f2bf(a0.w);
  ushort4 o1; o1.x = f2bf(a1.x); o1.y = f2bf(a1.y); o1.z = f2bf(a1.z); o1.w = f2bf(a1.w);
  unsigned short* dst = asp_bf + (size_t)row * Dq + lane * 8;
  *(ushort4*)dst = o0;
  *(ushort4*)(dst + 4) = o1;
#pragma unroll
  for (int o = 32; o; o >>= 1) sum += __shfl_xor(sum, o, 64);
  if (lane == 0) {
    float len = lenv[b];
    float scale = sqrtf(len);
    float f = 0.f;
    if (s < (int)len) f = 1.f / (scale * (sum / scale + 1e-4f));
    fac[row] = f;
  }
}

// ---- 64x64 tile, BK=64, dbuf, high-occupancy bf16 MFMA GEMM: C = A*B^T ----
// EPI 0: plain bf16 store (Gram matrix)
// EPI 2: ffn_inp = v*fac[row] + (inp+aspect)*mask  (weighted via Gram path)
// EPI 3: relu(v + bias) -> bf16
// EPI 4: 2*resid + relu(v + bias) -> fp32
struct EpiArgs {
  const float* fac;
  const unsigned short* inpb;
  const unsigned short* aspb;
  const float* lenv;
  const float* bias;
  const float* resid;
  float* outF;
  unsigned short* outBf;
};

template <int EPI, int MODE, int K>
__global__ __launch_bounds__(256, 5) void gemm_bf16(
    const unsigned short* __restrict__ Ag, const unsigned short* __restrict__ Bg,
    int M, int N, long strideA, long strideB, long strideOF, long strideOBf,
    EpiArgs e) {
  __shared__ unsigned short sA[2][64 * 64];  // 2 x 8 KB
  __shared__ unsigned short sB[2][64 * 64];  // 2 x 8 KB
  int b, bm, bn;
  if (MODE == 0) { b = blockIdx.x; bm = blockIdx.y; bn = blockIdx.z; }
  else           { b = 0; bm = blockIdx.x; bn = blockIdx.y; }
  const unsigned short* Ab = Ag + (size_t)b * strideA + (size_t)bm * 64 * K;
  const unsigned short* Bb = Bg + (size_t)b * strideB + (size_t)bn * 64 * K;
  int tid = threadIdx.x;
  int lane = tid & 63, wave = tid >> 6;
  int wm = (wave >> 1) * 32, wn = (wave & 1) * 32;
  int lr = lane & 15, lq = lane >> 4;
  int x7 = lr & 7;
  int l3 = lane >> 3, l7 = lane & 7;

  // coalesced swizzled staging: 2 instrs of 8 rows x 128B per operand per wave
  int r0 = wave * 16;
  const unsigned short* gA = Ab + (size_t)(r0 + l3) * K + (l7 ^ l3) * 8;
  const unsigned short* gB = Bb + (size_t)(r0 + l3) * K + (l7 ^ l3) * 8;
  int dbase0 = (r0 * 8 + lane) * 8;
  int dbase1 = ((r0 + 8) * 8 + lane) * 8;

  f32x4 acc[2][2] = {};

  auto issue = [&](int buf, int k0) {
    load_lds16(gA + k0, &sA[buf][dbase0]);
    load_lds16(gA + (size_t)8 * K + k0, &sA[buf][dbase1]);
    load_lds16(gB + k0, &sB[buf][dbase0]);
    load_lds16(gB + (size_t)8 * K + k0, &sB[buf][dbase1]);
  };

  const int nk = K >> 6;
  issue(0, 0);
#pragma unroll
  for (int it = 0; it < nk; ++it) {
    int cur = it & 1;
    __syncthreads();
    if (it + 1 < nk) issue(cur ^ 1, (it + 1) << 6);
#pragma unroll
    for (int c = 0; c < 2; ++c) {
      int g = c * 4 + lq;
      bf16x8 a0 = *(const bf16x8*)&sA[cur][((wm + lr) * 8 + (g ^ x7)) * 8];
      bf16x8 a1 = *(const bf16x8*)&sA[cur][((wm + 16 + lr) * 8 + (g ^ x7)) * 8];
      bf16x8 b0 = *(const bf16x8*)&sB[cur][((wn + lr) * 8 + (g ^ x7)) * 8];
      bf16x8 b1 = *(const bf16x8*)&sB[cur][((wn + 16 + lr) * 8 + (g ^ x7)) * 8];
      acc[0][0] = __builtin_amdgcn_mfma_f32_16x16x32_bf16(a0, b0, acc[0][0], 0, 0, 0);
      acc[0][1] = __builtin_amdgcn_mfma_f32_16x16x32_bf16(a0, b1, acc[0][1], 0, 0, 0);
      acc[1][0] = __builtin_amdgcn_mfma_f32_16x16x32_bf16(a1, b0, acc[1][0], 0, 0, 0);
      acc[1][1] = __builtin_amdgcn_mfma_f32_16x16x32_bf16(a1, b1, acc[1][1], 0, 0, 0);
    }
  }

#pragma unroll
  for (int mi = 0; mi < 2; ++mi) {
#pragma unroll
    for (int ni = 0; ni < 2; ++ni) {
#pragma unroll
      for (int i = 0; i < 4; ++i) {
        int r = bm * 64 + wm + mi * 16 + lq * 4 + i;
        int cc = bn * 64 + wn + ni * 16 + lr;
        float v = acc[mi][ni][i];
        if (EPI == 0) {
          e.outBf[(size_t)b * strideOBf + (size_t)r * N + cc] = f2bf(v);
        } else if (EPI == 2) {
          float f = e.fac[(size_t)b * M + r];
          int len = (int)e.lenv[b];
          size_t idx = (size_t)b * ((size_t)Sq * Dq) + (size_t)r * Dq + cc;
          float add = (r < len) ? (bf2f(e.inpb[idx]) + bf2f(e.aspb[idx])) : 0.f;
          float o = v * f + add;
          e.outF[(size_t)b * strideOF + (size_t)r * N + cc] = o;
          e.outBf[(size_t)b * strideOBf + (size_t)r * N + cc] = f2bf(o);
        } else if (EPI == 3) {
          float o = fmaxf(v + e.bias[cc], 0.f);
          e.outBf[(size_t)r * N + cc] = f2bf(o);
        } else {
          float o = fmaxf(v + e.bias[cc], 0.f);
          size_t idx = (size_t)r * N + cc;
          e.outF[idx] = 2.f * e.resid[idx] + o;
        }
      }
    }
  }
}

// ---- out[row] = final[row] / ||final[row]|| ----
__global__ void norm_kernel(const float* __restrict__ fin, float* __restrict__ out) {
  int row = blockIdx.x * 4 + (threadIdx.x >> 6);
  int lane = threadIdx.x & 63;
  const float* p = fin + (size_t)row * Dq;
  float4 v0 = *(const float4*)(p + lane * 8);
  float4 v1 = *(const float4*)(p + lane * 8 + 4);
  float ss = v0.x * v0.x + v0.y * v0.y + v0.z * v0.z + v0.w * v0.w +
             v1.x * v1.x + v1.y * v1.y + v1.z * v1.z + v1.w * v1.w;
#pragma unroll
  for (int o = 32; o; o >>= 1) ss += __shfl_xor(ss, o, 64);
  float rn = 1.f / sqrtf(ss);
  float* q = out + (size_t)row * Dq;
  v0.x *= rn; v0.y *= rn; v0.z *= rn; v0.w *= rn;
  v1.x *= rn; v1.y *= rn; v1.z *= rn; v1.w *= rn;
  *(float4*)(q + lane * 8) = v0;
  *(float4*)(q + lane * 8 + 4) = v1;
}

extern "C" void kernel_launch(void* const* d_in, const int* in_sizes, int n_in,
                              void* d_out, int out_size, void* d_ws, size_t ws_size,
                              hipStream_t stream) {
  const float* inp = (const float*)d_in[0];
  const float* inp_len = (const float*)d_in[1];
  const float* aspect = (const float*)d_in[2];
  const float* w1 = (const float*)d_in[3];
  const float* b1 = (const float*)d_in[4];
  const float* w2 = (const float*)d_in[5];
  const float* b2 = (const float*)d_in[6];
  float* out = (float*)d_out;

  char* W = (char*)d_ws;
  const size_t MB = 1ull << 20;
  unsigned short* inp_bf = (unsigned short*)(W + 0);        // 8 MB  [B][S][D]
  unsigned short* asp_bf = (unsigned short*)(W + 8 * MB);   // 8 MB  [B][S][D]
  unsigned short* inpT   = (unsigned short*)(W + 16 * MB);  // 8 MB  [B][D][S] (dead after GEMM-G)
  unsigned short* Gm     = (unsigned short*)(W + 24 * MB);  // 4 MB  [B][D][D] (dead after GEMM-W)
  float*          finalF = (float*)(W + 16 * MB);           // 16 MB (overlays dead inpT+Gm)
  float*          ffnF   = (float*)(W + 32 * MB);           // 16 MB [B*S][D] fp32
  unsigned short* ffnBf  = (unsigned short*)(W + 48 * MB);  // 8 MB
  unsigned short* o1b    = (unsigned short*)(W + 56 * MB);  // 8 MB
  unsigned short* w1bf   = (unsigned short*)(W + 64 * MB);  // 512 KB
  unsigned short* w2bf   = (unsigned short*)(W + 64 * MB + 512 * 1024);
  float*          colsum = (float*)(W + 65 * MB);           // 16 KB
  float*          fac    = (float*)(W + 65 * MB + 64 * 1024);  // 32 KB

  // prep
  hipMemsetAsync(colsum, 0, Bq * Dq * sizeof(float), stream);
  prep_inp<<<dim3(8, 32, 16), dim3(32, 8), 0, stream>>>(inp, inp_bf, inpT, colsum);
  convert_w<<<512, 256, 0, stream>>>(w1, w1bf, w2, w2bf);
  prep_asp<<<2048, 256, 0, stream>>>(aspect, colsum, inp_len, asp_bf, fac);

  // GEMM-G: G[b] = inpT[b] @ inpT[b]^T  (Gram, symmetric)  M=N=512 K=1024
  {
    EpiArgs e{};
    e.outBf = Gm;
    gemm_bf16<0, 0, 1024><<<dim3(8, 8, 8), 256, 0, stream>>>(
        inpT, inpT, 512, 512,
        (long)Dq * Sq, (long)Dq * Sq, 0, (long)Dq * Dq, e);
  }
  // GEMM-W: ffn_inp = fac ⊙ (asp @ G^T) + (inp+asp)*mask   M=1024 N=512 K=512
  // (G symmetric -> G works directly as B in A@B^T form)
  {
    EpiArgs e{};
    e.fac = fac; e.inpb = inp_bf; e.aspb = asp_bf; e.lenv = inp_len;
    e.outF = ffnF; e.outBf = ffnBf;
    gemm_bf16<2, 0, 512><<<dim3(8, 16, 8), 256, 0, stream>>>(
        asp_bf, Gm, 1024, 512,
        (long)Sq * Dq, (long)Dq * Dq, (long)Sq * Dq, (long)Sq * Dq, e);
  }
  // GEMM3: o1 = relu(ffn @ w1^T + b1)   M=8192 N=512 K=512
  {
    EpiArgs e{};
    e.bias = b1; e.outBf = o1b;
    gemm_bf16<3, 1, 512><<<dim3(128, 8), 256, 0, stream>>>(
        ffnBf, w1bf, 8192, 512, 0, 0, 0, 0, e);
  }
  // GEMM4: final = 2*ffn + relu(o1 @ w2^T + b2)   M=8192 N=512 K=512
  {
    EpiArgs e{};
    e.bias = b2; e.resid = ffnF; e.outF = finalF;
    gemm_bf16<4, 1, 512><<<dim3(128, 8), 256, 0, stream>>>(
        o1b, w2bf, 8192, 512, 0, 0, 0, 0, e);
  }
  // normalize rows
  norm_kernel<<<2048, 256, 0, stream>>>(finalF, out);
}